// Round 1
// baseline (132.098 us; speedup 1.0000x reference)
//
#include <hip/hip_runtime.h>
#include <hip/hip_bf16.h>
#include <stdint.h>

// BinarizedConv2d: out[d,h,w,o] = 1152 - 2*popcount(x_patch XOR w_filter)
// Derivation: per (tap,c) bit pair, 4xw - 2x - 2w + 1 == 1 - 2*(x^w).
// Zero-padded x positions contribute 1-2w, matching the reference (K counts
// all taps; xw/sx see zeros at padding). All values integer, exact in fp32.

#define D_    64
#define H_    32
#define W_    32
#define CIN_  128
#define COUT_ 128
#define KK_   1152   // CIN * 3 * 3

// ---------------------------------------------------------------------------
// Kernel 1: pack x (int32 0/1, [D,H,W,CIN]) -> xb[pos] = 4 x u32 bitmask.
// One wave per position; lane = channel; __ballot packs 64 bits at once.
// ---------------------------------------------------------------------------
__global__ __launch_bounds__(256) void pack_x_kernel(const int* __restrict__ x,
                                                     uint4* __restrict__ xb) {
    int gid  = blockIdx.x * 256 + threadIdx.x;
    int wave = gid >> 6;                 // global wave id == position index
    int lane = threadIdx.x & 63;
    long base = (long)wave * CIN_;
    unsigned long long b0 = __ballot(x[base + lane] != 0);
    unsigned long long b1 = __ballot(x[base + 64 + lane] != 0);
    if (lane == 0) {
        xb[wave] = make_uint4((unsigned)b0, (unsigned)(b0 >> 32),
                              (unsigned)b1, (unsigned)(b1 >> 32));
    }
}

// ---------------------------------------------------------------------------
// Kernel 2: pack w (float 0/1, [D,3,3,CIN,COUT]) -> wb[d][o][tap] = 4 x u32.
// Thread per (d,tap,o); lanes vary over o -> coalesced 512B reads per c-iter.
// ---------------------------------------------------------------------------
__global__ __launch_bounds__(256) void pack_w_kernel(const float* __restrict__ w,
                                                     uint4* __restrict__ wb) {
    int t  = blockIdx.x * 256 + threadIdx.x;   // t = (d*9 + tap)*128 + o
    int o  = t & 127;
    int dt = t >> 7;                           // d*9 + tap
    int d  = dt / 9;
    int tap = dt - d * 9;
    const float* wp = w + (long)dt * (CIN_ * COUT_) + o;
    unsigned w0 = 0, w1 = 0, w2 = 0, w3 = 0;
#pragma unroll
    for (int c = 0; c < 32; ++c)  { if (wp[(long)c * COUT_]         != 0.f) w0 |= 1u << c; }
#pragma unroll
    for (int c = 0; c < 32; ++c)  { if (wp[(long)(c + 32) * COUT_]  != 0.f) w1 |= 1u << c; }
#pragma unroll
    for (int c = 0; c < 32; ++c)  { if (wp[(long)(c + 64) * COUT_]  != 0.f) w2 |= 1u << c; }
#pragma unroll
    for (int c = 0; c < 32; ++c)  { if (wp[(long)(c + 96) * COUT_]  != 0.f) w3 |= 1u << c; }
    wb[(long)(d * COUT_ + o) * 9 + tap] = make_uint4(w0, w1, w2, w3);
}

// ---------------------------------------------------------------------------
// Kernel 3: main conv. Block = (d, 2-row tile); 256 threads:
//   o = tid & 127 (lane-consecutive couts -> coalesced stores)
//   grp = tid >> 7 (which of the 2 rows)
// x tile (4 rows x 34 cols, halo included, zeros at pad) staged in LDS and
// read wave-uniform (broadcast, no bank conflicts). Weights (36 u32) live in
// VGPRs for the whole kernel. Inner loop: 36 xor + 36 bcnt per output.
// ---------------------------------------------------------------------------
__global__ __launch_bounds__(256) void binconv_kernel(const uint4* __restrict__ xb,
                                                      const uint4* __restrict__ wb,
                                                      float* __restrict__ out) {
    __shared__ uint4 xbt[4][34];

    int bid  = blockIdx.x;
    int d    = bid >> 4;           // 16 tiles per d
    int tile = bid & 15;
    int h0   = tile * 2;
    int tid  = threadIdx.x;
    int o    = tid & 127;
    int grp  = tid >> 7;

    // Stage x tile: rows h0-1 .. h0+2, cols -1 .. 32 (zero at boundaries).
    if (tid < 4 * 34) {
        int r  = tid / 34;
        int cc = tid - r * 34;
        int hh = h0 - 1 + r;
        int ww = cc - 1;
        uint4 v = make_uint4(0u, 0u, 0u, 0u);
        if (hh >= 0 && hh < H_ && ww >= 0 && ww < W_)
            v = xb[(long)d * (H_ * W_) + hh * W_ + ww];
        xbt[r][cc] = v;
    }

    // Weights for this (d, o): 9 taps x 16B, resident in VGPRs.
    uint4 wv[9];
    const uint4* wp = wb + (long)(d * COUT_ + o) * 9;
#pragma unroll
    for (int t = 0; t < 9; ++t) wv[t] = wp[t];

    __syncthreads();

    int h = h0 + grp;
    float* op = out + ((long)d * (H_ * W_) + h * W_) * COUT_ + o;

    for (int iw = 0; iw < W_; ++iw) {
        int pop = 0;
#pragma unroll
        for (int i = 0; i < 3; ++i) {
#pragma unroll
            for (int j = 0; j < 3; ++j) {
                uint4 xa = xbt[grp + i][iw + j];   // wave-uniform -> broadcast
                uint4 wa = wv[i * 3 + j];
                pop += __popc(xa.x ^ wa.x);
                pop += __popc(xa.y ^ wa.y);
                pop += __popc(xa.z ^ wa.z);
                pop += __popc(xa.w ^ wa.w);
            }
        }
        op[(long)iw * COUT_] = (float)(KK_ - 2 * pop);
    }
}

// ---------------------------------------------------------------------------
extern "C" void kernel_launch(void* const* d_in, const int* in_sizes, int n_in,
                              void* d_out, int out_size, void* d_ws, size_t ws_size,
                              hipStream_t stream) {
    const int*   x = (const int*)d_in[0];    // bool -> int32 0/1 (assumed)
    const float* w = (const float*)d_in[1];  // float32 0/1
    float*       out = (float*)d_out;

    // Workspace layout: xb (65536 uint4 = 1 MB) | wb (73728 uint4 = 1.125 MB)
    uint4* xb = (uint4*)d_ws;
    uint4* wb = xb + (D_ * H_ * W_);

    // 1) pack x: one wave per position -> 65536 waves -> 16384 blocks
    pack_x_kernel<<<16384, 256, 0, stream>>>(x, xb);
    // 2) pack w: 64*9*128 = 73728 threads -> 288 blocks
    pack_w_kernel<<<288, 256, 0, stream>>>(w, wb);
    // 3) conv: 64 d * 16 row-tiles = 1024 blocks
    binconv_kernel<<<1024, 256, 0, stream>>>(xb, wb, out);
}

// Round 2
// 128.511 us; speedup vs baseline: 1.0279x; 1.0279x over previous
//
#include <hip/hip_runtime.h>
#include <hip/hip_bf16.h>
#include <stdint.h>

// BinarizedConv2d: out[d,h,w,o] = 1152 - 2*popcount(x_patch XOR w_filter)
// Per (tap,c) bit pair: 4xw - 2x - 2w + 1 == 1 - 2*(x^w); zero-padded x
// contributes 1-2w, matching the reference. Exact integers in fp32.
//
// Bit permutation (must match between pack_x and pack_w; popcount is
// order-agnostic): word k (k=0..3), bit j (j=0..31)  <->  channel 4j+k.

#define D_    64
#define H_    32
#define W_    32
#define CIN_  128
#define COUT_ 128
#define KK_   1152   // CIN * 3 * 3

// ---------------------------------------------------------------------------
// Kernel 1: pack x (int32 0/1, [D,H,W,CIN]) -> xb[pos] = uint4 bitmask.
// Thread = 4 channels (int4 load, 16B/lane). 32 threads per position;
// lanes 0..31 of a wave -> position p, lanes 32..63 -> p+1.
// ballot(v.x) low32 = word0 of p, high32 = word0 of p+1; etc.
// ---------------------------------------------------------------------------
__global__ __launch_bounds__(256) void pack_x_kernel(const int* __restrict__ x,
                                                     uint4* __restrict__ xb) {
    int gid = blockIdx.x * 256 + threadIdx.x;
    int pos = gid >> 5;            // position index (two per wave)
    int c4  = gid & 31;            // which int4 within the position
    const int4* xp = (const int4*)(x + (long)pos * CIN_) + c4;
    int4 v = *xp;
    unsigned long long b0 = __ballot(v.x != 0);
    unsigned long long b1 = __ballot(v.y != 0);
    unsigned long long b2 = __ballot(v.z != 0);
    unsigned long long b3 = __ballot(v.w != 0);
    int lane = threadIdx.x & 63;
    if (lane == 0)
        xb[pos] = make_uint4((unsigned)b0, (unsigned)b1, (unsigned)b2, (unsigned)b3);
    else if (lane == 32)
        xb[pos] = make_uint4((unsigned)(b0 >> 32), (unsigned)(b1 >> 32),
                             (unsigned)(b2 >> 32), (unsigned)(b3 >> 32));
}

// ---------------------------------------------------------------------------
// Kernel 2: pack w (float 0/1, [D,3,3,CIN,COUT]) -> wb as u32:
//   wb[(((d*128+o)*9 + tap)*4 + k]  = bits j of channel 4j+k.
// Thread = (dt, k, o); 32 coalesced loads per thread (lanes vary over o).
// 294912 threads -> 1152 blocks (4.5 blocks/CU; latency well hidden).
// ---------------------------------------------------------------------------
__global__ __launch_bounds__(256) void pack_w_kernel(const float* __restrict__ w,
                                                     unsigned* __restrict__ wb) {
    int t    = blockIdx.x * 256 + threadIdx.x;
    int o    = t & 127;
    int rest = t >> 7;
    int k    = rest & 3;
    int dt   = rest >> 2;          // d*9 + tap, 0..575
    int d    = dt / 9;
    int tap  = dt - d * 9;
    const float* wp = w + (long)dt * (CIN_ * COUT_) + o;
    unsigned m = 0;
#pragma unroll
    for (int j = 0; j < 32; ++j) {
        if (wp[(long)(4 * j + k) * COUT_] != 0.f) m |= 1u << j;
    }
    wb[(((long)d * COUT_ + o) * 9 + tap) * 4 + k] = m;
}

// ---------------------------------------------------------------------------
// Kernel 3: main conv. Block = (d, 2-row tile); 256 threads:
//   o = tid & 127 (coalesced stores), grp = tid >> 7 (which row).
// x tile (4 rows x 34 halo cols) in LDS, read wave-uniform (broadcast).
// Sliding 3-column register window: 3 ds_read_b128 per output (not 9).
// Weights (9 x uint4 = 36 VGPRs) resident for the whole kernel.
// ---------------------------------------------------------------------------
__global__ __launch_bounds__(256) void binconv_kernel(const uint4* __restrict__ xb,
                                                      const uint4* __restrict__ wb,
                                                      float* __restrict__ out) {
    __shared__ uint4 xbt[4][34];

    int bid  = blockIdx.x;
    int d    = bid >> 4;           // 16 two-row tiles per d
    int tile = bid & 15;
    int h0   = tile * 2;
    int tid  = threadIdx.x;
    int o    = tid & 127;
    int grp  = tid >> 7;

    // Stage x tile: rows h0-1 .. h0+2, cols -1 .. 32 (zeros at boundaries).
    if (tid < 4 * 34) {
        int r  = tid / 34;
        int cc = tid - r * 34;
        int hh = h0 - 1 + r;
        int ww = cc - 1;
        uint4 v = make_uint4(0u, 0u, 0u, 0u);
        if (hh >= 0 && hh < H_ && ww >= 0 && ww < W_)
            v = xb[(long)d * (H_ * W_) + hh * W_ + ww];
        xbt[r][cc] = v;
    }

    // Weights for this (d, o): 9 taps x 16B, resident in VGPRs.
    uint4 wv[9];
    const uint4* wp = wb + (long)(d * COUT_ + o) * 9;
#pragma unroll
    for (int t = 0; t < 9; ++t) wv[t] = wp[t];

    __syncthreads();

    int h = h0 + grp;
    float* op = out + ((long)d * (H_ * W_) + h * W_) * COUT_ + o;

    // Sliding window: ca/cb/cc_ = tile columns iw, iw+1, iw+2 (3 rows each).
    uint4 ca[3], cb[3], cc_[3];
#pragma unroll
    for (int i = 0; i < 3; ++i) {
        ca[i] = xbt[grp + i][0];
        cb[i] = xbt[grp + i][1];
    }

#pragma unroll
    for (int iw = 0; iw < W_; ++iw) {
#pragma unroll
        for (int i = 0; i < 3; ++i) cc_[i] = xbt[grp + i][iw + 2];
        int pop = 0;
#pragma unroll
        for (int i = 0; i < 3; ++i) {
            uint4 xa;
            uint4 w0 = wv[i * 3 + 0], w1 = wv[i * 3 + 1], w2 = wv[i * 3 + 2];
            xa = ca[i];
            pop += __popc(xa.x ^ w0.x) + __popc(xa.y ^ w0.y)
                 + __popc(xa.z ^ w0.z) + __popc(xa.w ^ w0.w);
            xa = cb[i];
            pop += __popc(xa.x ^ w1.x) + __popc(xa.y ^ w1.y)
                 + __popc(xa.z ^ w1.z) + __popc(xa.w ^ w1.w);
            xa = cc_[i];
            pop += __popc(xa.x ^ w2.x) + __popc(xa.y ^ w2.y)
                 + __popc(xa.z ^ w2.z) + __popc(xa.w ^ w2.w);
        }
        op[(long)iw * COUT_] = (float)(KK_ - 2 * pop);
        // rotate window (full unroll -> register renaming, no v_movs)
#pragma unroll
        for (int i = 0; i < 3; ++i) { ca[i] = cb[i]; cb[i] = cc_[i]; }
    }
}

// ---------------------------------------------------------------------------
extern "C" void kernel_launch(void* const* d_in, const int* in_sizes, int n_in,
                              void* d_out, int out_size, void* d_ws, size_t ws_size,
                              hipStream_t stream) {
    const int*   x   = (const int*)d_in[0];    // bool -> int32 0/1 (verified R1)
    const float* w   = (const float*)d_in[1];  // float32 0/1
    float*       out = (float*)d_out;

    // Workspace: xb (65536 uint4 = 1 MB) | wb (73728 uint4 = 1.125 MB)
    uint4*    xb = (uint4*)d_ws;
    unsigned* wb = (unsigned*)(xb + (D_ * H_ * W_));

    // 1) pack x: 65536 positions x 32 threads = 8192 blocks
    pack_x_kernel<<<8192, 256, 0, stream>>>(x, xb);
    // 2) pack w: 576 (d,tap) x 4 words x 128 o = 294912 threads = 1152 blocks
    pack_w_kernel<<<1152, 256, 0, stream>>>(w, wb);
    // 3) conv: 64 d * 16 row-tiles = 1024 blocks
    binconv_kernel<<<1024, 256, 0, stream>>>(xb, (const uint4*)wb, out);
}

// Round 4
// 128.035 us; speedup vs baseline: 1.0317x; 1.0037x over previous
//
#include <hip/hip_runtime.h>
#include <stdint.h>

// BinarizedConv2d: out[d,h,w,o] = 1152 - 2*popcount(x_patch XOR w_filter)
// Per (tap,c) bit pair: 4xw - 2x - 2w + 1 == 1 - 2*(x^w); zero-padded x
// contributes 1-2w, matching the reference. Exact integers in fp32.
//
// SINGLE plain dispatch (cooperative launch fails under this harness - R3).
// Each block is self-sufficient: packs its own x tile and its own d's
// weights into LDS (only __syncthreads needed), then computes.
// Bit permutation (same in both pack paths; popcount is order-agnostic):
// word k (k=0..3), bit j (j=0..31) <-> channel 4j+k.

#define D_    64
#define H_    32
#define W_    32
#define CIN_  128
#define COUT_ 128
#define KK_   1152   // CIN * 3 * 3

// 256 blocks x 1024 threads: block = (d = bid&63, tile = bid>>6).
// d in the LOW bits => same-d blocks are 64 apart => same XCD under typical
// round-robin dispatch => the 4x redundant raw-w reads hit that XCD's L2.
// 1024-thread blocks force VGPR<=128 => guaranteed 16 waves/CU residency.
__global__ __launch_bounds__(1024) void fused_kernel(const int* __restrict__ x,
                                                     const float* __restrict__ w,
                                                     float* __restrict__ out) {
    __shared__ uint4    xbt[10][34];   // rows h0-1..h0+8, cols -1..32 (packed)
    __shared__ unsigned wt[128][40];   // [o][tap*4+k], 36 padded to 40 (16B-aligned, 4-way-conflict reads)

    int tid  = threadIdx.x;
    int bid  = blockIdx.x;
    int d    = bid & 63;
    int tile = bid >> 6;
    int h0   = tile * 8;

    // Zero the 20 halo-column entries (cols 0 and 33 of each of 10 rows).
    if (tid < 20) {
        int r = tid >> 1, c = (tid & 1) ? 33 : 0;
        xbt[r][c] = make_uint4(0u, 0u, 0u, 0u);
    }

    // ---- Pack x tile: 10 rows x 32 cols x 32 int4-chunks = 10240 tasks ----
    // Lanes 0-31 of a wave -> position p, lanes 32-63 -> p+1; each
    // half-wave leader stores its own position's uint4 (all lanes ballot).
    const int* xd = x + (long)d * (H_ * W_ * CIN_);
#pragma unroll
    for (int it = 0; it < 10; ++it) {
        int t   = tid + it * 1024;
        int c4  = t & 31;
        int pl  = t >> 5;          // 0..319
        int r   = pl >> 5;         // 0..9
        int col = pl & 31;
        int hh  = h0 - 1 + r;
        int4 v = make_int4(0, 0, 0, 0);
        if (hh >= 0 && hh < H_)
            v = ((const int4*)(xd + (long)(hh * W_ + col) * CIN_))[c4];
        unsigned long long b0 = __ballot(v.x != 0);
        unsigned long long b1 = __ballot(v.y != 0);
        unsigned long long b2 = __ballot(v.z != 0);
        unsigned long long b3 = __ballot(v.w != 0);
        int lane = tid & 63;
        if (lane == 0)
            xbt[r][col + 1] = make_uint4((unsigned)b0, (unsigned)b1,
                                         (unsigned)b2, (unsigned)b3);
        else if (lane == 32)       // this lane's own (r,col) is the +1 position
            xbt[r][col + 1] = make_uint4((unsigned)(b0 >> 32), (unsigned)(b1 >> 32),
                                         (unsigned)(b2 >> 32), (unsigned)(b3 >> 32));
    }

    // ---- Pack this d's weights: 128 o x 9 tap x 4 k = 4608 words ----
    // Word (o,tap,k) = bits j of w[d,tap,ch=4j+k,o]. Lanes vary over o ->
    // each j-iteration is a 256B contiguous wave read.
    const float* wd = w + (long)d * (9 * CIN_ * COUT_);
    for (int t = tid; t < 4608; t += 1024) {
        int o    = t & 127;
        int rest = t >> 7;         // tap*4 + k, 0..35
        int tap  = rest >> 2;
        int k    = rest & 3;
        const float* wp = wd + (long)tap * (CIN_ * COUT_) + o;
        unsigned m = 0;
#pragma unroll
        for (int j = 0; j < 32; ++j)
            if (wp[(long)(4 * j + k) * COUT_] != 0.f) m |= 1u << j;
        wt[o][rest] = m;
    }

    __syncthreads();

    // ---- Conv: thread = (o = tid&127, grp = tid>>7 -> row h0+grp) ----
    // grp is wave-uniform (64 | 128) so xbt reads broadcast, conflict-free.
    int o   = tid & 127;
    int grp = tid >> 7;

    uint4 wv[9];
#pragma unroll
    for (int t = 0; t < 9; ++t)
        wv[t] = *(const uint4*)&wt[o][t * 4];

    int h = h0 + grp;
    float* op = out + ((long)d * (H_ * W_) + h * W_) * COUT_ + o;

    // Sliding 3-column register window: 3 ds_read_b128 per output.
    uint4 ca[3], cb[3], cc_[3];
#pragma unroll
    for (int i = 0; i < 3; ++i) {
        ca[i] = xbt[grp + i][0];
        cb[i] = xbt[grp + i][1];
    }

#pragma unroll
    for (int iw = 0; iw < W_; ++iw) {
#pragma unroll
        for (int i = 0; i < 3; ++i) cc_[i] = xbt[grp + i][iw + 2];
        int pop = 0;
#pragma unroll
        for (int i = 0; i < 3; ++i) {
            uint4 xa;
            uint4 w0 = wv[i * 3 + 0], w1 = wv[i * 3 + 1], w2 = wv[i * 3 + 2];
            xa = ca[i];
            pop += __popc(xa.x ^ w0.x) + __popc(xa.y ^ w0.y)
                 + __popc(xa.z ^ w0.z) + __popc(xa.w ^ w0.w);
            xa = cb[i];
            pop += __popc(xa.x ^ w1.x) + __popc(xa.y ^ w1.y)
                 + __popc(xa.z ^ w1.z) + __popc(xa.w ^ w1.w);
            xa = cc_[i];
            pop += __popc(xa.x ^ w2.x) + __popc(xa.y ^ w2.y)
                 + __popc(xa.z ^ w2.z) + __popc(xa.w ^ w2.w);
        }
        op[(long)iw * COUT_] = (float)(KK_ - 2 * pop);
#pragma unroll
        for (int i = 0; i < 3; ++i) { ca[i] = cb[i]; cb[i] = cc_[i]; }
    }
}

// ---------------------------------------------------------------------------
extern "C" void kernel_launch(void* const* d_in, const int* in_sizes, int n_in,
                              void* d_out, int out_size, void* d_ws, size_t ws_size,
                              hipStream_t stream) {
    const int*   x   = (const int*)d_in[0];    // bool -> int32 0/1 (verified R1)
    const float* w   = (const float*)d_in[1];  // float32 0/1
    float*       out = (float*)d_out;
    (void)d_ws; (void)ws_size;                 // no workspace needed

    fused_kernel<<<256, 1024, 0, stream>>>(x, w, out);
}